// Round 11
// baseline (7881.683 us; speedup 1.0000x reference)
//
#include <hip/hip_runtime.h>

#define NB 64      // batch
#define NL 512     // seq len
#define NT 64      // answer len
#define NH 512     // hidden
#define NE 256     // emb dim
#define NW 256     // attention weight dim

typedef __attribute__((ext_vector_type(8))) short bf16x8;
typedef __attribute__((ext_vector_type(4))) float f32x4;
typedef unsigned short u16;
typedef unsigned int u32;
typedef unsigned long long u64;

#define STM 0x4000400040004000ull   // bit14 of each u16 (never set in bf16 of |v|<2)
#define CLRM 0xBFFFBFFFBFFFBFFFull
#define MAGIC 0x600DF00Du

__device__ __forceinline__ float bf2f(u16 v){
  union { u32 u; float f; } x; x.u = ((u32)v) << 16; return x.f;
}
__device__ __forceinline__ u16 f2bf(float f){
  union { float f; u32 u; } x; x.f = f;
  return (u16)((x.u + 0x7FFFu + ((x.u >> 16) & 1u)) >> 16);
}
__device__ __forceinline__ float sigm(float x){ return 1.f / (1.f + __expf(-x)); }
__device__ __forceinline__ float tanh_(float x){ float e = __expf(2.f * x); return 1.f - 2.f / (e + 1.f); }

// device-scope (L3 coherence point) loads/stores — poll-on-data, no fences
__device__ __forceinline__ u64 ald64(const u64* p){
  return __hip_atomic_load(p, __ATOMIC_RELAXED, __HIP_MEMORY_SCOPE_AGENT);
}
__device__ __forceinline__ u32 ald32(const u32* p){
  return __hip_atomic_load(p, __ATOMIC_RELAXED, __HIP_MEMORY_SCOPE_AGENT);
}
__device__ __forceinline__ void ast32(u32* p, u32 v){
  __hip_atomic_store(p, v, __ATOMIC_RELAXED, __HIP_MEMORY_SCOPE_AGENT);
}
__device__ __forceinline__ void ast64(u64* p, u64 v){
  __hip_atomic_store(p, v, __ATOMIC_RELAXED, __HIP_MEMORY_SCOPE_AGENT);
}
__device__ __forceinline__ bf16x8 mk8(u64 a, u64 b){
  union { u64 q[2]; bf16x8 v; } u; u.q[0] = a; u.q[1] = b; return u.v;
}

// MEMORY heater: non-temporal streaming reads (bypass caches -> real fabric/
// HBM traffic) to lift the DF/fclk P-state while the persistent recurrence
// runs on a handful of CUs. Thread 0 checks done-flags between bursts.
__device__ __forceinline__ void mem_heater(const f32x4* __restrict__ src, int nvec,
                                           const u32* dflags, int nflags,
                                           u32* sink, u32* hstop){
  if(threadIdx.x == 0) *hstop = 0;
  __syncthreads();
  float acc = 0.f;
  int idx = (int)(((blockIdx.x * 4096u) + threadIdx.x) % (u32)nvec);
  for(;;){
#pragma unroll
    for(int i = 0; i < 32; ++i){
      const f32x4 v = __builtin_nontemporal_load(src + idx);
      acc += v[0] + v[1] + v[2] + v[3];
      idx += 256; if(idx >= nvec) idx -= nvec;
    }
    if(threadIdx.x == 0){
      u32 ok = 1;
      for(int q = 0; q < nflags; ++q) ok &= (ald32(dflags + q * 16) == MAGIC) ? 1u : 0u;
      *hstop = ok;
    }
    __syncthreads();
    if(*hstop) break;
    __syncthreads();
  }
  if(acc == 0.123456f) *sink = 1;   // defeats DCE; never true
}

__global__ void fill_kernel(u32* p, u32 v){
  p[blockIdx.x * 256 + threadIdx.x] = v;
}

// fp32 -> bf16 (round-to-nearest-even)
__global__ void cvt_kernel(const float* __restrict__ src, u16* __restrict__ dst, int n){
  const int i = blockIdx.x * 256 + threadIdx.x;
  if(i < n) dst[i] = f2bf(src[i]);
}

// ---------------------------------------------------------------------------
// Encoder (R8/R10-proven core): blocks 0..31 real — 4 independent btile
// groups of 8 blocks; wave = 16(batch) x 16(hidden) of all 4 gates; cell in
// registers; Whh REGISTER-RESIDENT; h in 2-slot ring with bit14-stamped
// poll-on-data sync. blend1 fold moved OFF the critical path (computed from
// h_{t-1} between store(h_t) and poll(h_t); final blend after the loop).
// Blocks 32..127: memory heater (fclk/DF P-state lift) until done flags set.
// ---------------------------------------------------------------------------
__global__ void __launch_bounds__(256, 1) enc_kernel(
    const int* __restrict__ ids, const u16* __restrict__ emb,
    const u16* __restrict__ Wih, const u16* __restrict__ Whh,
    const float* __restrict__ bih, const float* __restrict__ bhh,
    const u16* __restrict__ W1,  const float* __restrict__ b1,
    const float* __restrict__ heat, u16* hroll, u16* bl, u32* done)
{
  __shared__ u32 hstop;
  if(blockIdx.x >= 32){
    mem_heater((const f32x4*)heat, 10000 * NE / 4, done, 4, done + 128, &hstop);
    return;
  }
  const int lane = threadIdx.x & 63;
  const int col  = lane & 15;
  const int quad = lane >> 4;
  const int btile = blockIdx.x & 3;
  const int mtile = (blockIdx.x >> 2) * 4 + (threadIdx.x >> 6);
  const int j  = mtile * 16 + col;        // hidden index within a gate [0,512)
  const int ab = btile * 16 + col;        // A-row (batch) this lane loads

  float bias[4];
  const u16* wx[4];
  bf16x8 whr[16][4];                      // register-resident Whh fragments
#pragma unroll
  for(int g = 0; g < 4; ++g){
    const int row = g * NH + j;           // PyTorch gate order i,f,g,o
    bias[g] = bih[row] + bhh[row];
    wx[g] = Wih + (size_t)row * NE + quad * 8;
    const u16* whp = Whh + (size_t)row * NH + quad * 8;
#pragma unroll
    for(int i = 0; i < 16; ++i)
      whr[i][g] = *(const bf16x8*)(whp + 32 * i);
  }
  const int* idp = ids + ab * NL;         // ids is [B, L]
  const int n1 = mtile * 16 + col;        // blend1 column (mtile<16 only)
  const u16* w1r = W1 + (size_t)(mtile < 16 ? n1 : 0) * NH + quad * 8;
  const float b1f = (mtile < 16) ? b1[n1] : 0.f;
  float creg[4] = {0.f, 0.f, 0.f, 0.f};   // cell state, lane-owned

  u64 hb[32];                             // h_{t-1} fragment (stamp-cleaned)
  f32x4 acc[4];

  // x-part of t=0
  {
    const u16* xr = emb + (size_t)idp[0] * NE + quad * 8;
#pragma unroll
    for(int g = 0; g < 4; ++g) acc[g] = (f32x4){0.f, 0.f, 0.f, 0.f};
#pragma unroll
    for(int k0 = 0; k0 < NE; k0 += 32){
      const bf16x8 af = *(const bf16x8*)(xr + k0);
#pragma unroll
      for(int g = 0; g < 4; ++g)
        acc[g] = __builtin_amdgcn_mfma_f32_16x16x32_bf16(af, *(const bf16x8*)(wx[g] + k0), acc[g], 0, 0, 0);
    }
  }

  for(int t = 0; t < NL; ++t){
    // h part (hb = h_{t-1}) — all-register MFMA (critical path)
    if(t > 0){
#pragma unroll
      for(int i = 0; i < 16; ++i){
        const bf16x8 af = mk8(hb[2 * i], hb[2 * i + 1]);
#pragma unroll
        for(int g = 0; g < 4; ++g)
          acc[g] = __builtin_amdgcn_mfma_f32_16x16x32_bf16(af, whr[i][g], acc[g], 0, 0, 0);
      }
    }
    // epilogue: gates -> c (regs); h_t stamped + packed to u64 -> slot t&1
    const u32 st14 = ((u32)((t >> 1) & 1)) << 14;
    u16* ho = hroll + (t & 1) * (NB * NH);
#pragma unroll
    for(int r = 0; r < 4; ++r){
      const float gi = acc[0][r] + bias[0];
      const float gf = acc[1][r] + bias[1];
      const float gg = acc[2][r] + bias[2];
      const float go = acc[3][r] + bias[3];
      creg[r] = sigm(gf) * creg[r] + sigm(gi) * tanh_(gg);
      const u32 stv  = (u32)f2bf(sigm(go) * tanh_(creg[r])) | st14;
      const u32 pair = stv | (((u32)__shfl_xor((int)stv, 1, 64)) << 16);
      const u32 hi   = (u32)__shfl_xor((int)pair, 2, 64);
      if((col & 3) == 0){
        const int row = btile * 16 + quad * 4 + r;
        ast64((u64*)(ho + (size_t)row * NH + mtile * 16 + col),
              (u64)pair | ((u64)hi << 32));
      }
    }
    // OFF-critical-path while stores propagate: blend1(t-1) from hb (= h_{t-1})
    if(t > 0 && mtile < 16){
      f32x4 a2 = {0.f, 0.f, 0.f, 0.f};
#pragma unroll
      for(int i = 0; i < 16; ++i)
        a2 = __builtin_amdgcn_mfma_f32_16x16x32_bf16(mk8(hb[2 * i], hb[2 * i + 1]), *(const bf16x8*)(w1r + 32 * i), a2, 0, 0, 0);
#pragma unroll
      for(int r = 0; r < 4; ++r){
        const int b = btile * 16 + quad * 4 + r;
        bl[((size_t)(t - 1) * NB + b) * NW + n1] = f2bf(a2[r] + b1f);
      }
    }
    // overlap: x-part of t+1
    if(t + 1 < NL){
      const u16* xr = emb + (size_t)idp[t + 1] * NE + quad * 8;
#pragma unroll
      for(int g = 0; g < 4; ++g) acc[g] = (f32x4){0.f, 0.f, 0.f, 0.f};
#pragma unroll
      for(int k0 = 0; k0 < NE; k0 += 32){
        const bf16x8 af = *(const bf16x8*)(xr + k0);
#pragma unroll
        for(int g = 0; g < 4; ++g)
          acc[g] = __builtin_amdgcn_mfma_f32_16x16x32_bf16(af, *(const bf16x8*)(wx[g] + k0), acc[g], 0, 0, 0);
      }
    }
    // poll-on-data: load h_t fragment until every u16 has this step's stamp
    {
      const u16* ha = hroll + (t & 1) * (NB * NH) + (size_t)ab * NH + quad * 8;
      const u64 want = ((t >> 1) & 1) ? STM : 0ull;
      for(;;){
        bool ok = true;
#pragma unroll
        for(int i = 0; i < 16; ++i){
          const u64* p = (const u64*)(ha + 32 * i);
          hb[2 * i]     = ald64(p);
          hb[2 * i + 1] = ald64(p + 1);
          ok = ok && ((hb[2 * i] & STM) == want) && ((hb[2 * i + 1] & STM) == want);
        }
        if(__ballot(ok) == ~0ull) break;
        __builtin_amdgcn_s_sleep(1);
      }
#pragma unroll
      for(int i = 0; i < 32; ++i) hb[i] &= CLRM;
    }
  }
  // final blend1(NL-1) from hb (= h_{NL-1})
  if(mtile < 16){
    f32x4 a2 = {0.f, 0.f, 0.f, 0.f};
#pragma unroll
    for(int i = 0; i < 16; ++i)
      a2 = __builtin_amdgcn_mfma_f32_16x16x32_bf16(mk8(hb[2 * i], hb[2 * i + 1]), *(const bf16x8*)(w1r + 32 * i), a2, 0, 0, 0);
#pragma unroll
    for(int r = 0; r < 4; ++r){
      const int b = btile * 16 + quad * 4 + r;
      bl[((size_t)(NL - 1) * NB + b) * NW + n1] = f2bf(a2[r] + b1f);
    }
  }
  if(threadIdx.x == 0 && blockIdx.x < 4)
    ast32(done + btile * 16, MAGIC);
}

// ---------------------------------------------------------------------------
// Decoder LSTM (R10-proven): blocks 0..31 real — register-resident dWhh, 64
// write-once stamped h slots over the dead emb region. Slot t holds h_t.
// c0 = enc h_511 (hroll slot 1), h_{-1} = fp32 h0. Blocks 32..127: heater.
// ---------------------------------------------------------------------------
__global__ void __launch_bounds__(256, 1) dec_lstm_kernel(
    const u16* __restrict__ Whh, const float* __restrict__ bih, const float* __restrict__ bhh,
    const u16* __restrict__ hroll, const float* __restrict__ h0f,
    const float* __restrict__ heat, u16* hdX, u32* done)
{
  __shared__ u32 hstop;
  if(blockIdx.x >= 32){
    mem_heater((const f32x4*)heat, 10000 * NE / 4, done + 4 * 16, 1, done + 128, &hstop);
    return;
  }
  const int tid  = threadIdx.x;
  const int lane = tid & 63;
  const int wvl  = tid >> 6;
  const int col  = lane & 15;
  const int quad = lane >> 4;

  const int gw   = blockIdx.x * 4 + wvl;
  const int btile = gw >> 5;
  const int mtile = gw & 31;
  const int j  = mtile * 16 + col;
  const int ab = btile * 16 + col;
  float bias[4];
  bf16x8 whr[16][4];
  float creg[4];
#pragma unroll
  for(int g = 0; g < 4; ++g){
    const int row = g * NH + j;
    bias[g] = bih[row] + bhh[row];
    const u16* whp = Whh + (size_t)row * NH + quad * 8;
#pragma unroll
    for(int i = 0; i < 16; ++i)
      whr[i][g] = *(const bf16x8*)(whp + 32 * i);
  }
  // c0 = enc h_511: hroll slot 511&1 == 1, stamp bit set -> mask it
#pragma unroll
  for(int r = 0; r < 4; ++r){
    const int ci = (btile * 16 + quad * 4 + r) * NH + j;
    creg[r] = bf2f((u16)(hroll[(NB * NH) + ci] & 0xBFFFu));
  }

  for(int t = 0; t < NT; ++t){
    f32x4 z = {0.f, 0.f, 0.f, 0.f};
    f32x4 acc[4] = {z, z, z, z};
    if(t == 0){
      // h_{-1} = h0 (fp32, convert in regs)
      const float* hp = h0f + (size_t)ab * NH + quad * 8;
#pragma unroll
      for(int i = 0; i < 16; ++i){
        const f32x4 a0 = *(const f32x4*)(hp + 32 * i);
        const f32x4 a1 = *(const f32x4*)(hp + 32 * i + 4);
        bf16x8 af;
#pragma unroll
        for(int q = 0; q < 4; ++q){ af[q] = (short)f2bf(a0[q]); af[q + 4] = (short)f2bf(a1[q]); }
#pragma unroll
        for(int g = 0; g < 4; ++g)
          acc[g] = __builtin_amdgcn_mfma_f32_16x16x32_bf16(af, whr[i][g], acc[g], 0, 0, 0);
      }
    } else {
      // poll-on-data: slot t-1 (stamp always 1)
      u64 hb[32];
      const u16* ha = hdX + (size_t)(t - 1) * (NB * NH) + (size_t)ab * NH + quad * 8;
      for(;;){
        bool ok = true;
#pragma unroll
        for(int i = 0; i < 16; ++i){
          const u64* p = (const u64*)(ha + 32 * i);
          hb[2 * i]     = ald64(p);
          hb[2 * i + 1] = ald64(p + 1);
          ok = ok && ((hb[2 * i] & STM) == STM) && ((hb[2 * i + 1] & STM) == STM);
        }
        if(__ballot(ok) == ~0ull) break;
        __builtin_amdgcn_s_sleep(1);
      }
#pragma unroll
      for(int i = 0; i < 16; ++i){
        const bf16x8 af = mk8(hb[2 * i] & CLRM, hb[2 * i + 1] & CLRM);
#pragma unroll
        for(int g = 0; g < 4; ++g)
          acc[g] = __builtin_amdgcn_mfma_f32_16x16x32_bf16(af, whr[i][g], acc[g], 0, 0, 0);
      }
    }
    // epilogue: store h_t stamped into slot t
    u16* hn = hdX + (size_t)t * (NB * NH);
#pragma unroll
    for(int r = 0; r < 4; ++r){
      const float gi = acc[0][r] + bias[0];
      const float gf = acc[1][r] + bias[1];
      const float gg = acc[2][r] + bias[2];
      const float go = acc[3][r] + bias[3];
      creg[r] = sigm(gf) * creg[r] + sigm(gi) * tanh_(gg);
      const u32 stv  = (u32)f2bf(sigm(go) * tanh_(creg[r])) | 0x4000u;
      const u32 pair = stv | (((u32)__shfl_xor((int)stv, 1, 64)) << 16);
      const u32 hi   = (u32)__shfl_xor((int)pair, 2, 64);
      if((col & 3) == 0){
        const int row = btile * 16 + quad * 4 + r;
        ast64((u64*)(hn + (size_t)row * NH + mtile * 16 + col),
              (u64)pair | ((u64)hi << 32));
      }
    }
  }
  if(tid == 0 && blockIdx.x == 0)
    ast32(done + 4 * 16, MAGIC);
}

// ---------------------------------------------------------------------------
// Decoder attention (R10-proven): 4096 fully parallel blocks, one per (t,b).
// ---------------------------------------------------------------------------
__global__ void __launch_bounds__(256, 4) dec_attn_kernel(
    const float* __restrict__ W2, const float* __restrict__ b2,
    const float* __restrict__ vt, const float* __restrict__ vtb,
    const u16* __restrict__ bl,  const u16* __restrict__ hdX,
    float* __restrict__ out)
{
  __shared__ float h_f[NH];
  __shared__ float u_lds[NW];
  __shared__ float vt_lds[NW];
  __shared__ float red[8];

  const int tid  = threadIdx.x;
  const int lane = tid & 63;
  const int wvl  = tid >> 6;
  const int t = blockIdx.x >> 6;
  const int b = blockIdx.x & 63;

  // stage h_t[b] (stamped bf16) -> fp32 LDS
  {
    const u32 v = *(const u32*)(hdX + (size_t)t * (NB * NH) + (size_t)b * NH + 2 * tid);
    h_f[2 * tid]     = bf2f((u16)(v & 0xBFFFu));
    h_f[2 * tid + 1] = bf2f((u16)((v >> 16) & 0xBFFFu));
  }
  vt_lds[tid] = vt[tid];
  __syncthreads();

  // u[n] = b2[n] + h . W2[n,:]   (h broadcast from LDS)
  {
    const float* w2r = W2 + (size_t)tid * NH;
    float s = b2[tid];
#pragma unroll 8
    for(int k = 0; k < NH; ++k) s += h_f[k] * w2r[k];
    u_lds[tid] = s;
  }
  __syncthreads();

  // scores for l = tid and l = tid+256
  const float vtbf = vtb[0];
  float a0, a1;
#pragma unroll
  for(int e = 0; e < 2; ++e){
    const int l = tid + e * 256;
    const u16* br = bl + (size_t)(l * NB + b) * NW;
    float p = 0.f;
#pragma unroll 4
    for(int w = 0; w < NW; ++w)
      p += vt_lds[w] * tanh_(bf2f(br[w]) + u_lds[w]);
    if(e == 0) a0 = p + vtbf; else a1 = p + vtbf;
  }

  // log-softmax over L = 512 (2 values per thread, block-wide reduction)
  float mx = fmaxf(a0, a1);
#pragma unroll
  for(int off = 32; off > 0; off >>= 1) mx = fmaxf(mx, __shfl_xor(mx, off, 64));
  if(lane == 0) red[wvl] = mx;
  __syncthreads();
  mx = fmaxf(fmaxf(red[0], red[1]), fmaxf(red[2], red[3]));
  float es = __expf(a0 - mx) + __expf(a1 - mx);
#pragma unroll
  for(int off = 32; off > 0; off >>= 1) es += __shfl_xor(es, off, 64);
  if(lane == 0) red[4 + wvl] = es;
  __syncthreads();
  const float lse = mx + logf(red[4] + red[5] + red[6] + red[7]);
  out[((size_t)tid * NB + b) * NT + t]         = a0 - lse;
  out[((size_t)(tid + 256) * NB + b) * NT + t] = a1 - lse;
}

// ---------------------------------------------------------------------------
extern "C" void kernel_launch(void* const* d_in, const int* in_sizes, int n_in,
                              void* d_out, int out_size, void* d_ws, size_t ws_size,
                              hipStream_t stream)
{
  (void)in_sizes; (void)n_in; (void)out_size; (void)ws_size;
  const int*   ids  = (const int*)d_in[0];
  const float* emb  = (const float*)d_in[1];
  const float* eWih = (const float*)d_in[2];
  const float* eWhh = (const float*)d_in[3];
  const float* ebih = (const float*)d_in[4];
  const float* ebhh = (const float*)d_in[5];
  /* d_in[6] = dec_Wih: unused (decoder input is identically zero) */
  const float* dWhh = (const float*)d_in[7];
  const float* dbih = (const float*)d_in[8];
  const float* dbhh = (const float*)d_in[9];
  const float* W1   = (const float*)d_in[10];
  const float* b1   = (const float*)d_in[11];
  const float* W2   = (const float*)d_in[12];
  const float* b2   = (const float*)d_in[13];
  const float* vt   = (const float*)d_in[14];
  const float* vtb  = (const float*)d_in[15];
  const float* h0   = (const float*)d_in[16];

  // workspace: ~27.5 MB. Region X is bf16-emb during enc, then re-used as the
  // decoder's 64 write-once h slots (stamp bit14 disambiguates).
  char* ws = (char*)d_ws;
  u16* bl     = (u16*)ws; ws += (size_t)NL * NB * NW * 2;    // blend1 bf16  16.78 MB
  u16* hroll  = (u16*)ws; ws += (size_t)2 * NB * NH * 2;     // enc h ring   0.13 MB
  u16* X      = (u16*)ws; ws += (size_t)10000 * NE * 2;      // emb_b / hdec 5.12 MB
  u16* eWih_b = (u16*)ws; ws += (size_t)4 * NH * NE * 2;     // 1.05 MB
  u16* eWhh_b = (u16*)ws; ws += (size_t)4 * NH * NH * 2;     // 2.10 MB
  u16* dWhh_b = (u16*)ws; ws += (size_t)4 * NH * NH * 2;     // 2.10 MB
  u16* W1_b   = (u16*)ws; ws += (size_t)NW * NH * 2;         // 0.26 MB
  u32* done   = (u32*)ws; ws += 1024;                        // done flags + sink

  // enc ring slots pre-filled with stamp-1 pattern; done flags zeroed
  hipLaunchKernelGGL(fill_kernel, dim3((2 * NB * NH / 2) / 256), dim3(256), 0, stream,
                     (u32*)hroll, 0x40004000u);
  hipLaunchKernelGGL(fill_kernel, dim3(1), dim3(256), 0, stream, done, 0u);
  hipLaunchKernelGGL(cvt_kernel, dim3(10000), dim3(256), 0, stream, emb,  X,      10000 * NE);
  hipLaunchKernelGGL(cvt_kernel, dim3(2048),  dim3(256), 0, stream, eWih, eWih_b, 4 * NH * NE);
  hipLaunchKernelGGL(cvt_kernel, dim3(4096),  dim3(256), 0, stream, eWhh, eWhh_b, 4 * NH * NH);
  hipLaunchKernelGGL(cvt_kernel, dim3(4096),  dim3(256), 0, stream, dWhh, dWhh_b, 4 * NH * NH);
  hipLaunchKernelGGL(cvt_kernel, dim3(512),   dim3(256), 0, stream, W1,   W1_b,   NW * NH);

  hipLaunchKernelGGL(enc_kernel, dim3(128), dim3(256), 0, stream,
                     ids, X, eWih_b, eWhh_b, ebih, ebhh, W1_b, b1, emb, hroll, bl, done);
  hipLaunchKernelGGL(dec_lstm_kernel, dim3(128), dim3(256), 0, stream,
                     dWhh_b, dbih, dbhh, hroll, h0, emb, X, done);
  hipLaunchKernelGGL(dec_attn_kernel, dim3(NT * NB), dim3(256), 0, stream,
                     W2, b2, vt, vtb, bl, X, (float*)d_out);
}

// Round 12
// 6124.463 us; speedup vs baseline: 1.2869x; 1.2869x over previous
//
#include <hip/hip_runtime.h>

#define NB 64      // batch
#define NL 512     // seq len
#define NT 64      // answer len
#define NH 512     // hidden
#define NE 256     // emb dim
#define NW 256     // attention weight dim

typedef __attribute__((ext_vector_type(8))) short bf16x8;
typedef __attribute__((ext_vector_type(4))) float f32x4;
typedef unsigned short u16;
typedef unsigned int u32;
typedef unsigned long long u64;

#define STM 0x4000400040004000ull   // bit14 of each u16 (never set in bf16 of |v|<2)
#define CLRM 0xBFFFBFFFBFFFBFFFull

__device__ __forceinline__ float bf2f(u16 v){
  union { u32 u; float f; } x; x.u = ((u32)v) << 16; return x.f;
}
__device__ __forceinline__ u16 f2bf(float f){
  union { float f; u32 u; } x; x.f = f;
  return (u16)((x.u + 0x7FFFu + ((x.u >> 16) & 1u)) >> 16);
}
__device__ __forceinline__ float sigm(float x){ return 1.f / (1.f + __expf(-x)); }
__device__ __forceinline__ float tanh_(float x){ float e = __expf(2.f * x); return 1.f - 2.f / (e + 1.f); }

// device-scope (L3 coherence point) loads/stores — poll-on-data, no fences
__device__ __forceinline__ u64 ald64(const u64* p){
  return __hip_atomic_load(p, __ATOMIC_RELAXED, __HIP_MEMORY_SCOPE_AGENT);
}
__device__ __forceinline__ void ast64(u64* p, u64 v){
  __hip_atomic_store(p, v, __ATOMIC_RELAXED, __HIP_MEMORY_SCOPE_AGENT);
}
__device__ __forceinline__ bf16x8 mk8(u64 a, u64 b){
  union { u64 q[2]; bf16x8 v; } u; u.q[0] = a; u.q[1] = b; return u.v;
}

__global__ void fill_kernel(u32* p, u32 v){
  p[blockIdx.x * 256 + threadIdx.x] = v;
}

// fp32 -> bf16 (round-to-nearest-even)
__global__ void cvt_kernel(const float* __restrict__ src, u16* __restrict__ dst, int n){
  const int i = blockIdx.x * 256 + threadIdx.x;
  if(i < n) dst[i] = f2bf(src[i]);
}

// ---------------------------------------------------------------------------
// Encoder (R10 core + COOPERATIVE POLL): 32 blocks x 256 threads, 4
// independent btile groups of 8 blocks. Wave = 16(batch) x 16(hidden) of all
// 4 gates; cell in registers; Whh REGISTER-RESIDENT; h in a 2-slot ring with
// bit14-stamped poll-on-data sync. NEW: the 4 waves of a block need the SAME
// 16-row A-fragment, so each wave polls only 8 of the 32 u64s (cutting the
// serialized device-scope load chain 4x) and the block shares via LDS
// (double-buffered, one barrier per step).
// ---------------------------------------------------------------------------
__global__ void __launch_bounds__(256, 1) enc_kernel(
    const int* __restrict__ ids, const u16* __restrict__ emb,
    const u16* __restrict__ Wih, const u16* __restrict__ Whh,
    const float* __restrict__ bih, const float* __restrict__ bhh,
    const u16* __restrict__ W1,  const float* __restrict__ b1,
    u16* hroll, u16* bl)
{
  __shared__ u64 hsh[2][64 * 33];         // [slot][lane*33 + chunk], padded

  const int lane = threadIdx.x & 63;
  const int wvl  = threadIdx.x >> 6;      // 0..3
  const int col  = lane & 15;
  const int quad = lane >> 4;
  const int btile = blockIdx.x & 3;
  const int mtile = (blockIdx.x >> 2) * 4 + wvl;
  const int j  = mtile * 16 + col;        // hidden index within a gate [0,512)
  const int ab = btile * 16 + col;        // A-row (batch) this lane loads

  float bias[4];
  const u16* wx[4];
  bf16x8 whr[16][4];                      // register-resident Whh fragments
#pragma unroll
  for(int g = 0; g < 4; ++g){
    const int row = g * NH + j;           // PyTorch gate order i,f,g,o
    bias[g] = bih[row] + bhh[row];
    wx[g] = Wih + (size_t)row * NE + quad * 8;
    const u16* whp = Whh + (size_t)row * NH + quad * 8;
#pragma unroll
    for(int i = 0; i < 16; ++i)
      whr[i][g] = *(const bf16x8*)(whp + 32 * i);
  }
  const int* idp = ids + ab * NL;         // ids is [B, L]
  const int n1 = mtile * 16 + col;        // blend1 column (mtile<16 only)
  const u16* w1r = W1 + (size_t)(mtile < 16 ? n1 : 0) * NH + quad * 8;
  const float b1f = (mtile < 16) ? b1[n1] : 0.f;
  float creg[4] = {0.f, 0.f, 0.f, 0.f};   // cell state, lane-owned

  u64 hb[32];                             // h_t fragment (stamp-cleaned)
  f32x4 acc[4];

  // x-part of t=0
  {
    const u16* xr = emb + (size_t)idp[0] * NE + quad * 8;
#pragma unroll
    for(int g = 0; g < 4; ++g) acc[g] = (f32x4){0.f, 0.f, 0.f, 0.f};
#pragma unroll
    for(int k0 = 0; k0 < NE; k0 += 32){
      const bf16x8 af = *(const bf16x8*)(xr + k0);
#pragma unroll
      for(int g = 0; g < 4; ++g)
        acc[g] = __builtin_amdgcn_mfma_f32_16x16x32_bf16(af, *(const bf16x8*)(wx[g] + k0), acc[g], 0, 0, 0);
    }
  }

  for(int t = 0; t < NL; ++t){
    // h part (hb = h_{t-1}, shared via LDS last iteration) — all-register
    if(t > 0){
#pragma unroll
      for(int i = 0; i < 16; ++i){
        const bf16x8 af = mk8(hb[2 * i], hb[2 * i + 1]);
#pragma unroll
        for(int g = 0; g < 4; ++g)
          acc[g] = __builtin_amdgcn_mfma_f32_16x16x32_bf16(af, whr[i][g], acc[g], 0, 0, 0);
      }
    }
    // epilogue: gates -> c (regs); h_t stamped + packed to u64 -> slot t&1
    const u32 st14 = ((u32)((t >> 1) & 1)) << 14;
    u16* ho = hroll + (t & 1) * (NB * NH);
#pragma unroll
    for(int r = 0; r < 4; ++r){
      const float gi = acc[0][r] + bias[0];
      const float gf = acc[1][r] + bias[1];
      const float gg = acc[2][r] + bias[2];
      const float go = acc[3][r] + bias[3];
      creg[r] = sigm(gf) * creg[r] + sigm(gi) * tanh_(gg);
      const u32 stv  = (u32)f2bf(sigm(go) * tanh_(creg[r])) | st14;
      const u32 pair = stv | (((u32)__shfl_xor((int)stv, 1, 64)) << 16);
      const u32 hi   = (u32)__shfl_xor((int)pair, 2, 64);
      if((col & 3) == 0){
        const int row = btile * 16 + quad * 4 + r;
        ast64((u64*)(ho + (size_t)row * NH + mtile * 16 + col),
              (u64)pair | ((u64)hi << 32));
      }
    }
    // overlap: x-part of t+1 while stores become visible
    if(t + 1 < NL){
      const u16* xr = emb + (size_t)idp[t + 1] * NE + quad * 8;
#pragma unroll
      for(int g = 0; g < 4; ++g) acc[g] = (f32x4){0.f, 0.f, 0.f, 0.f};
#pragma unroll
      for(int k0 = 0; k0 < NE; k0 += 32){
        const bf16x8 af = *(const bf16x8*)(xr + k0);
#pragma unroll
        for(int g = 0; g < 4; ++g)
          acc[g] = __builtin_amdgcn_mfma_f32_16x16x32_bf16(af, *(const bf16x8*)(wx[g] + k0), acc[g], 0, 0, 0);
      }
    }
    // cooperative poll-on-data: wave wvl polls chunks [wvl*4, wvl*4+4) (8
    // u64s) until every u16 carries this step's stamp; share via LDS.
    {
      const u16* ha = hroll + (t & 1) * (NB * NH) + (size_t)ab * NH + quad * 8;
      const u64 want = ((t >> 1) & 1) ? STM : 0ull;
      const int i0 = wvl * 4;
      u64 tmp[8];
      for(;;){
        bool ok = true;
#pragma unroll
        for(int i = 0; i < 4; ++i){
          const u64* p = (const u64*)(ha + 32 * (i0 + i));
          tmp[2 * i]     = ald64(p);
          tmp[2 * i + 1] = ald64(p + 1);
          ok = ok && ((tmp[2 * i] & STM) == want) && ((tmp[2 * i + 1] & STM) == want);
        }
        if(__ballot(ok) == ~0ull) break;
        __builtin_amdgcn_s_sleep(1);
      }
      u64* hs = &hsh[t & 1][lane * 33];
#pragma unroll
      for(int i = 0; i < 4; ++i){
        hs[2 * (i0 + i)]     = tmp[2 * i]     & CLRM;
        hs[2 * (i0 + i) + 1] = tmp[2 * i + 1] & CLRM;
      }
      __syncthreads();
#pragma unroll
      for(int i = 0; i < 32; ++i) hb[i] = hs[i];
    }
    // blend1[t] fold (normal stores — consumed after kernel boundary)
    if(mtile < 16){
      f32x4 a2 = {0.f, 0.f, 0.f, 0.f};
#pragma unroll
      for(int i = 0; i < 16; ++i)
        a2 = __builtin_amdgcn_mfma_f32_16x16x32_bf16(mk8(hb[2 * i], hb[2 * i + 1]), *(const bf16x8*)(w1r + 32 * i), a2, 0, 0, 0);
#pragma unroll
      for(int r = 0; r < 4; ++r){
        const int b = btile * 16 + quad * 4 + r;
        bl[((size_t)t * NB + b) * NW + n1] = f2bf(a2[r] + b1f);
      }
    }
  }
}

// ---------------------------------------------------------------------------
// Decoder LSTM (R10 core + COOPERATIVE POLL): 32 blocks x 256 threads,
// register-resident dWhh, 64 write-once stamped h slots over the dead emb
// region. Slot t holds h_t. c0 = enc h_511 (hroll slot 1), h_{-1} = fp32 h0.
// ---------------------------------------------------------------------------
__global__ void __launch_bounds__(256, 1) dec_lstm_kernel(
    const u16* __restrict__ Whh, const float* __restrict__ bih, const float* __restrict__ bhh,
    const u16* __restrict__ hroll, const float* __restrict__ h0f,
    u16* hdX)
{
  __shared__ u64 hsh[2][64 * 33];

  const int tid  = threadIdx.x;
  const int lane = tid & 63;
  const int wvl  = tid >> 6;
  const int col  = lane & 15;
  const int quad = lane >> 4;

  const int gw   = blockIdx.x * 4 + wvl;
  const int btile = gw >> 5;
  const int mtile = gw & 31;
  const int j  = mtile * 16 + col;
  const int ab = btile * 16 + col;
  float bias[4];
  bf16x8 whr[16][4];
  float creg[4];
#pragma unroll
  for(int g = 0; g < 4; ++g){
    const int row = g * NH + j;
    bias[g] = bih[row] + bhh[row];
    const u16* whp = Whh + (size_t)row * NH + quad * 8;
#pragma unroll
    for(int i = 0; i < 16; ++i)
      whr[i][g] = *(const bf16x8*)(whp + 32 * i);
  }
  // c0 = enc h_511: hroll slot 511&1 == 1, stamp bit set -> mask it
#pragma unroll
  for(int r = 0; r < 4; ++r){
    const int ci = (btile * 16 + quad * 4 + r) * NH + j;
    creg[r] = bf2f((u16)(hroll[(NB * NH) + ci] & 0xBFFFu));
  }

  for(int t = 0; t < NT; ++t){
    f32x4 z = {0.f, 0.f, 0.f, 0.f};
    f32x4 acc[4] = {z, z, z, z};
    if(t == 0){
      // h_{-1} = h0 (fp32, convert in regs)
      const float* hp = h0f + (size_t)ab * NH + quad * 8;
#pragma unroll
      for(int i = 0; i < 16; ++i){
        const f32x4 a0 = *(const f32x4*)(hp + 32 * i);
        const f32x4 a1 = *(const f32x4*)(hp + 32 * i + 4);
        bf16x8 af;
#pragma unroll
        for(int q = 0; q < 4; ++q){ af[q] = (short)f2bf(a0[q]); af[q + 4] = (short)f2bf(a1[q]); }
#pragma unroll
        for(int g = 0; g < 4; ++g)
          acc[g] = __builtin_amdgcn_mfma_f32_16x16x32_bf16(af, whr[i][g], acc[g], 0, 0, 0);
      }
    } else {
      // cooperative poll-on-data: slot t-1 (stamp always 1); 8 u64s per wave
      u64 hb[32];
      {
        const u16* ha = hdX + (size_t)(t - 1) * (NB * NH) + (size_t)ab * NH + quad * 8;
        const int i0 = wvl * 4;
        u64 tmp[8];
        for(;;){
          bool ok = true;
#pragma unroll
          for(int i = 0; i < 4; ++i){
            const u64* p = (const u64*)(ha + 32 * (i0 + i));
            tmp[2 * i]     = ald64(p);
            tmp[2 * i + 1] = ald64(p + 1);
            ok = ok && ((tmp[2 * i] & STM) == STM) && ((tmp[2 * i + 1] & STM) == STM);
          }
          if(__ballot(ok) == ~0ull) break;
          __builtin_amdgcn_s_sleep(1);
        }
        u64* hs = &hsh[t & 1][lane * 33];
#pragma unroll
        for(int i = 0; i < 4; ++i){
          hs[2 * (i0 + i)]     = tmp[2 * i]     & CLRM;
          hs[2 * (i0 + i) + 1] = tmp[2 * i + 1] & CLRM;
        }
        __syncthreads();
#pragma unroll
        for(int i = 0; i < 32; ++i) hb[i] = hs[i];
      }
#pragma unroll
      for(int i = 0; i < 16; ++i){
        const bf16x8 af = mk8(hb[2 * i], hb[2 * i + 1]);
#pragma unroll
        for(int g = 0; g < 4; ++g)
          acc[g] = __builtin_amdgcn_mfma_f32_16x16x32_bf16(af, whr[i][g], acc[g], 0, 0, 0);
      }
    }
    // epilogue: store h_t stamped into slot t
    u16* hn = hdX + (size_t)t * (NB * NH);
#pragma unroll
    for(int r = 0; r < 4; ++r){
      const float gi = acc[0][r] + bias[0];
      const float gf = acc[1][r] + bias[1];
      const float gg = acc[2][r] + bias[2];
      const float go = acc[3][r] + bias[3];
      creg[r] = sigm(gf) * creg[r] + sigm(gi) * tanh_(gg);
      const u32 stv  = (u32)f2bf(sigm(go) * tanh_(creg[r])) | 0x4000u;
      const u32 pair = stv | (((u32)__shfl_xor((int)stv, 1, 64)) << 16);
      const u32 hi   = (u32)__shfl_xor((int)pair, 2, 64);
      if((col & 3) == 0){
        const int row = btile * 16 + quad * 4 + r;
        ast64((u64*)(hn + (size_t)row * NH + mtile * 16 + col),
              (u64)pair | ((u64)hi << 32));
      }
    }
  }
}

// ---------------------------------------------------------------------------
// Decoder attention (R10-proven): 4096 fully parallel blocks, one per (t,b).
// ---------------------------------------------------------------------------
__global__ void __launch_bounds__(256, 4) dec_attn_kernel(
    const float* __restrict__ W2, const float* __restrict__ b2,
    const float* __restrict__ vt, const float* __restrict__ vtb,
    const u16* __restrict__ bl,  const u16* __restrict__ hdX,
    float* __restrict__ out)
{
  __shared__ float h_f[NH];
  __shared__ float u_lds[NW];
  __shared__ float vt_lds[NW];
  __shared__ float red[8];

  const int tid  = threadIdx.x;
  const int lane = tid & 63;
  const int wvl  = tid >> 6;
  const int t = blockIdx.x >> 6;
  const int b = blockIdx.x & 63;

  // stage h_t[b] (stamped bf16) -> fp32 LDS
  {
    const u32 v = *(const u32*)(hdX + (size_t)t * (NB * NH) + (size_t)b * NH + 2 * tid);
    h_f[2 * tid]     = bf2f((u16)(v & 0xBFFFu));
    h_f[2 * tid + 1] = bf2f((u16)((v >> 16) & 0xBFFFu));
  }
  vt_lds[tid] = vt[tid];
  __syncthreads();

  // u[n] = b2[n] + h . W2[n,:]   (h broadcast from LDS)
  {
    const float* w2r = W2 + (size_t)tid * NH;
    float s = b2[tid];
#pragma unroll 8
    for(int k = 0; k < NH; ++k) s += h_f[k] * w2r[k];
    u_lds[tid] = s;
  }
  __syncthreads();

  // scores for l = tid and l = tid+256
  const float vtbf = vtb[0];
  float a0, a1;
#pragma unroll
  for(int e = 0; e < 2; ++e){
    const int l = tid + e * 256;
    const u16* br = bl + (size_t)(l * NB + b) * NW;
    float p = 0.f;
#pragma unroll 4
    for(int w = 0; w < NW; ++w)
      p += vt_lds[w] * tanh_(bf2f(br[w]) + u_lds[w]);
    if(e == 0) a0 = p + vtbf; else a1 = p + vtbf;
  }

  // log-softmax over L = 512 (2 values per thread, block-wide reduction)
  float mx = fmaxf(a0, a1);
#pragma unroll
  for(int off = 32; off > 0; off >>= 1) mx = fmaxf(mx, __shfl_xor(mx, off, 64));
  if(lane == 0) red[wvl] = mx;
  __syncthreads();
  mx = fmaxf(fmaxf(red[0], red[1]), fmaxf(red[2], red[3]));
  float es = __expf(a0 - mx) + __expf(a1 - mx);
#pragma unroll
  for(int off = 32; off > 0; off >>= 1) es += __shfl_xor(es, off, 64);
  if(lane == 0) red[4 + wvl] = es;
  __syncthreads();
  const float lse = mx + logf(red[4] + red[5] + red[6] + red[7]);
  out[((size_t)tid * NB + b) * NT + t]         = a0 - lse;
  out[((size_t)(tid + 256) * NB + b) * NT + t] = a1 - lse;
}

// ---------------------------------------------------------------------------
extern "C" void kernel_launch(void* const* d_in, const int* in_sizes, int n_in,
                              void* d_out, int out_size, void* d_ws, size_t ws_size,
                              hipStream_t stream)
{
  (void)in_sizes; (void)n_in; (void)out_size; (void)ws_size;
  const int*   ids  = (const int*)d_in[0];
  const float* emb  = (const float*)d_in[1];
  const float* eWih = (const float*)d_in[2];
  const float* eWhh = (const float*)d_in[3];
  const float* ebih = (const float*)d_in[4];
  const float* ebhh = (const float*)d_in[5];
  /* d_in[6] = dec_Wih: unused (decoder input is identically zero) */
  const float* dWhh = (const float*)d_in[7];
  const float* dbih = (const float*)d_in[8];
  const float* dbhh = (const float*)d_in[9];
  const float* W1   = (const float*)d_in[10];
  const float* b1   = (const float*)d_in[11];
  const float* W2   = (const float*)d_in[12];
  const float* b2   = (const float*)d_in[13];
  const float* vt   = (const float*)d_in[14];
  const float* vtb  = (const float*)d_in[15];
  const float* h0   = (const float*)d_in[16];

  // workspace: ~27.5 MB. Region X is bf16-emb during enc, then re-used as the
  // decoder's 64 write-once h slots (stamp bit14 disambiguates).
  char* ws = (char*)d_ws;
  u16* bl     = (u16*)ws; ws += (size_t)NL * NB * NW * 2;    // blend1 bf16  16.78 MB
  u16* hroll  = (u16*)ws; ws += (size_t)2 * NB * NH * 2;     // enc h ring   0.13 MB
  u16* X      = (u16*)ws; ws += (size_t)10000 * NE * 2;      // emb_b / hdec 5.12 MB
  u16* eWih_b = (u16*)ws; ws += (size_t)4 * NH * NE * 2;     // 1.05 MB
  u16* eWhh_b = (u16*)ws; ws += (size_t)4 * NH * NH * 2;     // 2.10 MB
  u16* dWhh_b = (u16*)ws; ws += (size_t)4 * NH * NH * 2;     // 2.10 MB
  u16* W1_b   = (u16*)ws; ws += (size_t)NW * NH * 2;         // 0.26 MB

  // enc ring slots pre-filled with stamp-1 pattern (first writes use stamp 0)
  hipLaunchKernelGGL(fill_kernel, dim3((2 * NB * NH / 2) / 256), dim3(256), 0, stream,
                     (u32*)hroll, 0x40004000u);
  hipLaunchKernelGGL(cvt_kernel, dim3(10000), dim3(256), 0, stream, emb,  X,      10000 * NE);
  hipLaunchKernelGGL(cvt_kernel, dim3(2048),  dim3(256), 0, stream, eWih, eWih_b, 4 * NH * NE);
  hipLaunchKernelGGL(cvt_kernel, dim3(4096),  dim3(256), 0, stream, eWhh, eWhh_b, 4 * NH * NH);
  hipLaunchKernelGGL(cvt_kernel, dim3(4096),  dim3(256), 0, stream, dWhh, dWhh_b, 4 * NH * NH);
  hipLaunchKernelGGL(cvt_kernel, dim3(512),   dim3(256), 0, stream, W1,   W1_b,   NW * NH);

  hipLaunchKernelGGL(enc_kernel, dim3(32), dim3(256), 0, stream,
                     ids, X, eWih_b, eWhh_b, ebih, ebhh, W1_b, b1, hroll, bl);
  hipLaunchKernelGGL(dec_lstm_kernel, dim3(32), dim3(256), 0, stream,
                     dWhh_b, dbih, dbhh, hroll, h0, X);
  hipLaunchKernelGGL(dec_attn_kernel, dim3(NT * NB), dim3(256), 0, stream,
                     W2, b2, vt, vtb, bl, X, (float*)d_out);
}